// Round 8
// baseline (155.109 us; speedup 1.0000x reference)
//
#include <hip/hip_runtime.h>
#include <math.h>

#define N 1024
#define B_ 8
#define T_ 256
#define NREP 4
#define NFFTBLK 1024   // FFT blocks: b = L>>7, mgroup = L&127 (same-mgroup -> same XCD)
#define NSTAT 64       // M-stats blocks appended after the FFT blocks

// ws float offsets (keep total footprint tiny: poisoned-ws lines are cold+dirty)
#define OFF_SF      0        // float2 sf[1024]                     [0,2048)
#define OFF_TA      2048     // float2 TA[256][3] (W_1024^p,^2p,^3p)[2048,5120) -- 3072 floats
#define OFF_ROWSUM  5120     // 8*1024                              [5120,13312)
#define ZERO_START  13312
#define OFF_COLSUMM 13312    // 1024
#define OFF_SUMM2   14336
#define OFF_MAXM    14337
#define OFF_SUMMT   14344    // 8
#define OFF_SUMTT   14352    // 8
#define OFF_COLT    14368    // 8*NREP*1024 = 32768                 [14368,47136)
#define ZERO_END    47136

__device__ __forceinline__ float wave_sum(float v) {
    #pragma unroll
    for (int o = 32; o > 0; o >>= 1) v += __shfl_down(v, o, 64);
    return v;
}
__device__ __forceinline__ float wave_max(float v) {
    #pragma unroll
    for (int o = 32; o > 0; o >>= 1) v = fmaxf(v, __shfl_down(v, o, 64));
    return v;
}

// forward radix-4 DIF butterfly, twiddles (W^pos, W^2pos, W^3pos) applied to outputs 1..3
#define BFLY4(x0, x1, x2, x3, w1, w2, w3)                                   \
    do {                                                                    \
        float t0r = x0.x + x2.x, t0i = x0.y + x2.y;                         \
        float t1r = x0.x - x2.x, t1i = x0.y - x2.y;                         \
        float t2r = x1.x + x3.x, t2i = x1.y + x3.y;                         \
        float t3r = x1.x - x3.x, t3i = x1.y - x3.y;                         \
        float y1r = t1r + t3i, y1i = t1i - t3r;                             \
        float y2r = t0r - t2r, y2i = t0i - t2i;                             \
        float y3r = t1r - t3i, y3i = t1i + t3r;                             \
        x0 = make_float2(t0r + t2r, t0i + t2i);                             \
        x1 = make_float2(y1r * w1.x - y1i * w1.y, y1r * w1.y + y1i * w1.x); \
        x2 = make_float2(y2r * w2.x - y2i * w2.y, y2r * w2.y + y2i * w2.x); \
        x3 = make_float2(y3r * w3.x - y3i * w3.y, y3r * w3.y + y3i * w3.x); \
    } while (0)

#define BFLY4_NOTW(x0, x1, x2, x3)                                          \
    do {                                                                    \
        float t0r = x0.x + x2.x, t0i = x0.y + x2.y;                         \
        float t1r = x0.x - x2.x, t1i = x0.y - x2.y;                         \
        float t2r = x1.x + x3.x, t2i = x1.y + x3.y;                         \
        float t3r = x1.x - x3.x, t3i = x1.y - x3.y;                         \
        x0 = make_float2(t0r + t2r, t0i + t2i);                             \
        x1 = make_float2(t1r + t3i, t1i - t3r);                             \
        x2 = make_float2(t0r - t2r, t0i - t2i);                             \
        x3 = make_float2(t1r - t3i, t1i + t3r);                             \
    } while (0)

#define WSYNC()                                  \
    do {                                         \
        __builtin_amdgcn_s_waitcnt(0xc07f);      \
        __builtin_amdgcn_wave_barrier();         \
    } while (0)

// sf + twiddle table + zero accumulators + zero out: 4 blocks x 256 threads
__global__ __launch_bounds__(T_) void k_prep(float* ws, float* out) {
    const int e = blockIdx.x * T_ + threadIdx.x;   // 0..1023
    {
        double ang = -2.0 * 337.927 * 1.5 * (double)(e - 512);
        double s, c;
        sincos(ang, &s, &c);
        ws[OFF_SF + 2 * e] = (float)c;
        ws[OFF_SF + 2 * e + 1] = (float)s;
    }
    if (e < 256) {
        double a1 = -2.0 * M_PI * (double)e / 1024.0;
        double s1, c1, s2, c2, s3, c3;
        sincos(a1, &s1, &c1);
        sincos(2.0 * a1, &s2, &c2);
        sincos(3.0 * a1, &s3, &c3);
        float* p = ws + OFF_TA + e * 6;
        p[0] = (float)c1; p[1] = (float)s1;
        p[2] = (float)c2; p[3] = (float)s2;
        p[4] = (float)c3; p[5] = (float)s3;
    }
    for (int j = ZERO_START + e; j < ZERO_END; j += 4 * T_) ws[j] = 0.f;
    if (e == 0) out[0] = 0.f;
}

// grid = NFFTBLK + NSTAT blocks of 256.
//   L < 1024: FFT block; b = L>>7, mgroup = L&127; wave wv handles row m = 4*mgroup+wv
//             (wave 0 of mgroup 0 also does m=512). Wave-synchronous 1024-pt FFT:
//             16 elems/lane, stages (256,64) in-reg -> LDS xchg -> (16) -> xchg -> (4,1).
//   L >= 1024: M-stats (colsumM / sumM2 / maxM), 16 rows per block.
__global__ __launch_bounds__(T_, 4) void k_row(const float* __restrict__ pred,
                                               const float* __restrict__ M,
                                               float* __restrict__ ws) {
    __shared__ float2 Y[N];
    __shared__ float2 XB[4][N];
    const int tid = threadIdx.x;
    const int lane = tid & 63;
    const int wv = tid >> 6;
    const int L = blockIdx.x;

    if (L >= NFFTBLK) {
        // ---- M-stats ----
        float* sred = (float*)&Y[0];
        const int r0 = (L - NFFTBLK) * 16;
        float cs[4] = {0.f, 0.f, 0.f, 0.f};
        float sq = 0.f, mx = 0.f;
        for (int r = 0; r < 16; ++r) {
            const float* row = M + (size_t)(r0 + r) * N;
            #pragma unroll
            for (int q = 0; q < 4; ++q) {
                float v = row[tid + T_ * q];
                cs[q] += v;
                sq += v * v;
                mx = fmaxf(mx, v);
            }
        }
        #pragma unroll
        for (int q = 0; q < 4; ++q) atomicAdd(&ws[OFF_COLSUMM + tid + T_ * q], cs[q]);
        sq = wave_sum(sq);
        mx = wave_max(mx);
        if (lane == 0) { sred[wv] = sq; sred[4 + wv] = mx; }
        __syncthreads();
        if (tid == 0) {
            atomicAdd(&ws[OFF_SUMM2], sred[0] + sred[1] + sred[2] + sred[3]);
            float X = fmaxf(fmaxf(sred[4], sred[5]), fmaxf(sred[6], sred[7]));
            atomicMax((unsigned int*)ws + OFF_MAXM, __float_as_uint(X));
        }
        return;
    }

    const int b = L >> 7;
    const int mgroup = L & 127;

    // stage y once per block
    {
        const float* pr = pred + (size_t)b * 2 * N;
        #pragma unroll
        for (int q = 0; q < 4; ++q) {
            int j = tid + T_ * q;
            Y[j] = make_float2(pr[j], pr[N + j]);
        }
    }
    __syncthreads();

    const float2* sfg = (const float2*)(ws + OFF_SF);
    const float2* TA  = (const float2*)(ws + OFF_TA);
    float2* Xw = XB[wv];
    const int g = lane & 15, a = lane >> 4;
    const int c0 = ((lane & 3) << 4) | (((lane >> 2) & 3) << 2) | (lane >> 4);

    float cr[16];
    #pragma unroll
    for (int i = 0; i < 16; ++i) cr[i] = 0.f;
    float mtacc = 0.f, ttacc = 0.f;

    const int nrow = (mgroup == 0 && wv == 0) ? 2 : 1;
    for (int rr = 0; rr < nrow; ++rr) {
        const int m = (rr == 0) ? (4 * mgroup + wv) : 512;
        const int mm = (N - m) & (N - 1);
        const float wgt = (mm == m) ? 1.f : 2.f;

        // product (elements j = lane + 64u) -- all in registers
        float2 x[16];
        #pragma unroll
        for (int u = 0; u < 16; ++u) {
            int j = lane + 64 * u;
            int s = (j - m + 512) & (N - 1);
            float2 ya = Y[j], yb = Y[s], sv = sfg[j];
            float prr = ya.x * yb.x - ya.y * yb.y;
            float pii = ya.x * yb.y + ya.y * yb.x;
            x[u] = make_float2(prr * sv.x - pii * sv.y, prr * sv.y + pii * sv.x);
        }
        // stage 0 (h=256): butterfly k on (x[k],x[k+4],x[k+8],x[k+12]), pos = lane+64k
        #pragma unroll
        for (int k = 0; k < 4; ++k) {
            int p3 = 3 * (lane + 64 * k);
            float2 w1 = TA[p3], w2 = TA[p3 + 1], w3 = TA[p3 + 2];
            BFLY4(x[k], x[k + 4], x[k + 8], x[k + 12], w1, w2, w3);
        }
        // stage 1 (h=64): pos = lane, W_256^pos = TA[4*lane]; same triple all 4 bflies
        {
            int p3 = 3 * (4 * lane);
            float2 w1 = TA[p3], w2 = TA[p3 + 1], w3 = TA[p3 + 2];
            #pragma unroll
            for (int k = 0; k < 4; ++k)
                BFLY4(x[4 * k], x[4 * k + 1], x[4 * k + 2], x[4 * k + 3], w1, w2, w3);
        }
        // Exchange 1: position p = 64u + lane stored at p ^ ((p>>6)&15) = 64u + (lane^u)
        #pragma unroll
        for (int u = 0; u < 16; ++u) Xw[64 * u + (lane ^ u)] = x[u];
        WSYNC();
        // read positions 64g + 16j + (4a+l): idx = 64g + 16j + ((4a+l)^g)
        float2 v[16];
        #pragma unroll
        for (int l = 0; l < 4; ++l) {
            #pragma unroll
            for (int j = 0; j < 4; ++j)
                v[4 * l + j] = Xw[64 * g + 16 * j + ((4 * a + l) ^ g)];
        }
        // stage 2 (h=16): pos = 4a+l, W_64^pos = TA[16*pos]; butterfly over j
        #pragma unroll
        for (int l = 0; l < 4; ++l) {
            int p3 = 3 * (16 * (4 * a + l));
            float2 w1 = TA[p3], w2 = TA[p3 + 1], w3 = TA[p3 + 2];
            BFLY4(v[4 * l], v[4 * l + 1], v[4 * l + 2], v[4 * l + 3], w1, w2, w3);
        }
        // Exchange 2: p = 64g+16j+4a+l at p ^ ((p>>4)&15) ^ ((p>>8)&3)
        WSYNC();
        #pragma unroll
        for (int l = 0; l < 4; ++l) {
            #pragma unroll
            for (int j = 0; j < 4; ++j)
                Xw[64 * g + 16 * j + ((4 * a + l) ^ (4 * (g & 3) + j) ^ (g >> 2))] = v[4 * l + j];
        }
        WSYNC();
        // read positions q = 16*lane + r: idx = 16*lane + (r ^ (lane&15) ^ (lane>>4))
        float2 z[16];
        #pragma unroll
        for (int r = 0; r < 16; ++r)
            z[r] = Xw[16 * lane + (r ^ (lane & 15) ^ (lane >> 4))];
        // stage 3 (h=4): pos3 = l on (z[l], z[l+4], z[l+8], z[l+12]); W_16 constants
        {
            const float2 C1a = {0.92387953f, -0.38268343f}, C1b = {0.70710678f, -0.70710678f},
                         C1c = {0.38268343f, -0.92387953f};
            const float2 C2a = {0.70710678f, -0.70710678f}, C2b = {0.0f, -1.0f},
                         C2c = {-0.70710678f, -0.70710678f};
            const float2 C3a = {0.38268343f, -0.92387953f}, C3b = {-0.70710678f, -0.70710678f},
                         C3c = {-0.92387953f, 0.38268343f};
            BFLY4_NOTW(z[0], z[4], z[8], z[12]);
            BFLY4(z[1], z[5], z[9], z[13], C1a, C1b, C1c);
            BFLY4(z[2], z[6], z[10], z[14], C2a, C2b, C2c);
            BFLY4(z[3], z[7], z[11], z[15], C3a, C3b, C3c);
        }
        // stage 4 (h=1): (z[4r'], .. z[4r'+3]), no twiddles
        #pragma unroll
        for (int r4 = 0; r4 < 4; ++r4)
            BFLY4_NOTW(z[4 * r4], z[4 * r4 + 1], z[4 * r4 + 2], z[4 * r4 + 3]);

        // magnitudes + reductions; position p = 16*lane + r holds X[k],
        // c = (digit-reverse4(p)) ^ 512 = 256*((r&3)^2) + 64*(r>>2) + c0
        float rs = 0.f;
        const float* M1 = M + (size_t)m * N;
        const float* M2 = M + (size_t)mm * N;
        #pragma unroll
        for (int r = 0; r < 16; ++r) {
            float mag = 1.5f * sqrtf(z[r].x * z[r].x + z[r].y * z[r].y);
            int c = 256 * ((r & 3) ^ 2) + 64 * (r >> 2) + c0;
            rs += mag;
            ttacc += wgt * mag * mag;
            float ms = M1[c];
            if (mm != m) ms += M2[c];
            mtacc += ms * mag;
            cr[r] += wgt * mag;
        }
        rs = wave_sum(rs);
        if (lane == 0) {
            ws[OFF_ROWSUM + b * N + m] = rs;
            if (mm != m) ws[OFF_ROWSUM + b * N + mm] = rs;
        }
        WSYNC();   // guard Xw reuse if this wave runs a second row
    }

    mtacc = wave_sum(mtacc);
    ttacc = wave_sum(ttacc);
    if (lane == 0) {
        atomicAdd(&ws[OFF_SUMMT + b], mtacc);
        atomicAdd(&ws[OFF_SUMTT + b], ttacc);
    }

    // merge the 4 waves' column sums in LDS (reuse XB[0]), one global atomic/column
    __syncthreads();
    float* colM = (float*)&XB[0][0];
    #pragma unroll
    for (int q = 0; q < 4; ++q) colM[tid + T_ * q] = 0.f;
    __syncthreads();
    #pragma unroll
    for (int r = 0; r < 16; ++r) {
        int c = 256 * ((r & 3) ^ 2) + 64 * (r >> 2) + c0;
        atomicAdd(&colM[c], cr[r]);
    }
    __syncthreads();
    {
        float* colT = ws + OFF_COLT + (size_t)(b * NREP + (mgroup & (NREP - 1))) * N;
        #pragma unroll
        for (int q = 0; q < 4; ++q) {
            int c = tid + T_ * q;
            atomicAdd(&colT[c], colM[c]);
        }
    }
}

__global__ __launch_bounds__(T_) void k_final(float* ws, float* out) {
    __shared__ double redn[4], redd[4];
    const int b = blockIdx.x;
    const int t = threadIdx.x;
    const int wid = t >> 6, lane = t & 63;
    const float* rowsum = ws + OFF_ROWSUM + (size_t)b * N;
    double num = 0.0, den = 0.0;
    #pragma unroll
    for (int q = 0; q < 4; ++q) {
        int j = t + 256 * q;
        double r = (double)rowsum[j];
        float ct = 0.f;
        #pragma unroll
        for (int rep = 0; rep < NREP; ++rep)
            ct += ws[OFF_COLT + (size_t)(b * NREP + rep) * N + j];
        num += (double)ws[OFF_COLSUMM + j] * r;
        den += (double)ct * r;
    }
    #pragma unroll
    for (int o = 32; o > 0; o >>= 1) {
        num += __shfl_down(num, o, 64);
        den += __shfl_down(den, o, 64);
    }
    if (lane == 0) { redn[wid] = num; redd[wid] = den; }
    __syncthreads();
    if (t == 0) {
        double NUM = redn[0] + redn[1] + redn[2] + redn[3];
        double DEN = redd[0] + redd[1] + redd[2] + redd[3];
        double mu = NUM / DEN;
        double r = (double)ws[OFF_SUMM2] - 2.0 * mu * (double)ws[OFF_SUMMT + b]
                 + mu * mu * (double)ws[OFF_SUMTT + b];
        float mx = ws[OFF_MAXM];  // float bits written via uint atomicMax
        double norm = 1048576.0 * (double)mx * (double)mx;
        atomicAdd(out, (float)(sqrt(r / norm) / 8.0));
    }
}

extern "C" void kernel_launch(void* const* d_in, const int* in_sizes, int n_in,
                              void* d_out, int out_size, void* d_ws, size_t ws_size,
                              hipStream_t stream) {
    const float* pred = (const float*)d_in[0];   // [8, 2048]
    const float* M = (const float*)d_in[2];      // [1024, 1024]
    float* ws = (float*)d_ws;
    float* out = (float*)d_out;

    k_prep<<<4, T_, 0, stream>>>(ws, out);
    k_row<<<NFFTBLK + NSTAT, T_, 0, stream>>>(pred, M, ws);
    k_final<<<B_, T_, 0, stream>>>(ws, out);
}